// Round 6
// baseline (99.798 us; speedup 1.0000x reference)
//
#include <hip/hip_runtime.h>
#include <hip/hip_bf16.h>

#define Nn 8192
#define Mm 1024
#define Dd 1024

typedef __attribute__((ext_vector_type(8))) short short8;
typedef __attribute__((ext_vector_type(4))) short short4v;
typedef __attribute__((ext_vector_type(4))) float f32x4;
typedef __attribute__((ext_vector_type(4))) unsigned uint4v;

// round-to-nearest-even fp32 -> bf16 (bit pattern as short)
__device__ __forceinline__ short f2bf(float f) {
  unsigned u = __builtin_bit_cast(unsigned, f);
  u += 0x7fffu + ((u >> 16) & 1u);
  return (short)(u >> 16);
}

// packed RNE fp32x2 -> bf16x2 (hardware cvt)
__device__ __forceinline__ unsigned cvt2bf(float lo, float hi) {
  unsigned r;
  asm("v_cvt_pk_bf16_f32 %0, %1, %2" : "=v"(r) : "v"(lo), "v"(hi));
  return r;
}

// 8 fp32 -> short8 of bf16
__device__ __forceinline__ short8 cvt8(float4 a, float4 b) {
  uint4v q;
  q[0] = cvt2bf(a.x, a.y);
  q[1] = cvt2bf(a.z, a.w);
  q[2] = cvt2bf(b.x, b.y);
  q[3] = cvt2bf(b.z, b.w);
  return __builtin_bit_cast(short8, q);
}

// ---------------- kernel 1: B'[m,d] = bf16(u*w3 + w1); c[m] = u . w2 ----------------
__global__ void prep_b_kernel(const float* __restrict__ u, const float* __restrict__ w,
                              short* __restrict__ Bp, float* __restrict__ cvec) {
  int m = blockIdx.x;      // 1024 blocks
  int t = threadIdx.x;     // 256 threads, 4 elems each
  float4 uv = ((const float4*)(u + (size_t)m * Dd))[t];
  float4 w1 = ((const float4*)(w))[t];
  float4 w2 = ((const float4*)(w + Dd))[t];
  float4 w3 = ((const float4*)(w + 2 * Dd))[t];
  float p = uv.x * w2.x + uv.y * w2.y + uv.z * w2.z + uv.w * w2.w;
  short4v o;
  o[0] = f2bf(fmaf(uv.x, w3.x, w1.x));
  o[1] = f2bf(fmaf(uv.y, w3.y, w1.y));
  o[2] = f2bf(fmaf(uv.z, w3.z, w1.z));
  o[3] = f2bf(fmaf(uv.w, w3.w, w1.w));
  *(short4v*)(Bp + (size_t)m * Dd + t * 4) = o;

#pragma unroll
  for (int off = 32; off > 0; off >>= 1) p += __shfl_down(p, off);
  __shared__ float sred[4];
  if ((t & 63) == 0) sred[t >> 6] = p;
  __syncthreads();
  if (t == 0) cvec[m] = sred[0] + sred[1] + sred[2] + sred[3];
}

// ---------------- kernel 2: wave-private GEMM  S = bf16(h) @ B'^T + c ----------------
// NO LDS, NO barriers. 2048 independent waves, each owns a 64x64 output tile.
// Fragments loaded DIRECTLY from global: one wave A-frag load touches 16 full
// 128B cachelines (lane l -> row l&15, 32B chunk l>>4) -- fully coalesced.
// B' (2MB) is L2-resident; A n-strip shared by 4 consecutive same-XCD blocks.
// fp32->bf16 inline via v_cvt_pk_bf16_f32. Depth-1 register pipeline with two
// NAMED load sets (X/Y, static indexing per rule #20); compiler schedules
// loads under the other set's MFMAs; latency hidden by 8 waves/CU TLP.
__global__ __launch_bounds__(256) void gemm_wave_kernel(
    const float* __restrict__ h,   // N x D fp32
    const short* __restrict__ Bp,  // M x D bf16 (B')
    const float* __restrict__ cvec,// M
    float* __restrict__ out)       // N x M fp32
{
  const int bid = blockIdx.x;
  // bijective XCD swizzle: 512 blocks, 64 per XCD; 4 consecutive = one A-strip
  const int swz  = (bid & 7) * 64 + (bid >> 3);
  const int lane = threadIdx.x & 63;
  const int wid  = threadIdx.x >> 6;
  const int np = swz >> 2;              // 0..127 : 64-row A panel
  const int mp = (swz & 3) * 4 + wid;   // 0..15  : 64-col B panel

  const int lr = lane & 15;             // fragment row within 16
  const int lk = lane >> 4;             // k-chunk 0..3 (8 elems each)

  const float* Ab = h  + (size_t)(np * 64 + lr) * Dd + lk * 8;
  const short*  Bb = Bp + (size_t)(mp * 64 + lr) * Dd + lk * 8;

  f32x4 acc[4][4] = {};

  float4 aX[4][2]; short8 bX[4];
  float4 aY[4][2]; short8 bY[4];

#define LOADSET(aS, bS, koff) do { \
    _Pragma("unroll") \
    for (int i = 0; i < 4; ++i) { \
      const float* ap_ = Ab + (size_t)i * 16 * Dd + (koff); \
      aS[i][0] = *(const float4*)(ap_); \
      aS[i][1] = *(const float4*)(ap_ + 4); \
      bS[i]    = *(const short8*)(Bb + (size_t)i * 16 * Dd + (koff)); \
    } \
  } while (0)

#define COMPUTE(aS, bS) do { \
    short8 af_[4]; \
    _Pragma("unroll") \
    for (int i = 0; i < 4; ++i) af_[i] = cvt8(aS[i][0], aS[i][1]); \
    _Pragma("unroll") \
    for (int i = 0; i < 4; ++i) \
      _Pragma("unroll") \
      for (int j = 0; j < 4; ++j) \
        acc[i][j] = __builtin_amdgcn_mfma_f32_16x16x32_bf16(af_[i], bS[j], acc[i][j], 0, 0, 0); \
  } while (0)

  // 32 K-steps of 32 elems; unroll-2 with swapped X/Y roles (no reg copies)
  LOADSET(aX, bX, 0);
#pragma unroll 1
  for (int k = 0; k < 30; k += 2) {
    LOADSET(aY, bY, (k + 1) * 32);
    COMPUTE(aX, bX);
    LOADSET(aX, bX, (k + 2) * 32);
    COMPUTE(aY, bY);
  }
  LOADSET(aY, bY, 31 * 32);
  COMPUTE(aX, bX);
  COMPUTE(aY, bY);
#undef LOADSET
#undef COMPUTE

  // --- epilogue: S[n,m] = acc + c[m] (proven C/D mapping) ---
  const int n0 = np * 64 + lk * 4;
  const int m0 = mp * 64 + lr;
#pragma unroll
  for (int j = 0; j < 4; ++j) {
    const float cm = cvec[m0 + j * 16];
#pragma unroll
    for (int i = 0; i < 4; ++i) {
      float* op = out + (size_t)(n0 + i * 16) * Mm + m0 + j * 16;
#pragma unroll
      for (int r = 0; r < 4; ++r)
        op[(size_t)r * Mm] = acc[i][j][r] + cm;
    }
  }
}

extern "C" void kernel_launch(void* const* d_in, const int* in_sizes, int n_in,
                              void* d_out, int out_size, void* d_ws, size_t ws_size,
                              hipStream_t stream) {
  const float* h = (const float*)d_in[0];
  const float* u = (const float*)d_in[1];
  const float* w = (const float*)d_in[2];
  float* out = (float*)d_out;

  // workspace layout: B' bf16 (2MB) | c fp32 (4KB)
  short* Bp  = (short*)d_ws;
  float* cvec = (float*)(Bp + (size_t)Mm * Dd);

  prep_b_kernel<<<Mm, 256, 0, stream>>>(u, w, Bp, cvec);
  gemm_wave_kernel<<<(Nn / 64) * (Mm / 64) / 4, 256, 0, stream>>>(h, Bp, cvec, out);
}

// Round 7
// 37.808 us; speedup vs baseline: 2.6396x; 2.6396x over previous
//
#include <hip/hip_runtime.h>
#include <hip/hip_bf16.h>

#define Nn 8192
#define Mm 1024
#define Dd 1024

typedef __attribute__((ext_vector_type(8))) short short8;
typedef __attribute__((ext_vector_type(4))) short short4v;
typedef __attribute__((ext_vector_type(4))) float f32x4;
typedef __attribute__((ext_vector_type(4))) unsigned uint4v;

typedef const __attribute__((address_space(1))) void* gas_p;
typedef __attribute__((address_space(3))) void* las_p;

// round-to-nearest-even fp32 -> bf16 (bit pattern as short)
__device__ __forceinline__ short f2bf(float f) {
  unsigned u = __builtin_bit_cast(unsigned, f);
  u += 0x7fffu + ((u >> 16) & 1u);
  return (short)(u >> 16);
}

// packed RNE fp32x2 -> bf16x2 (hardware cvt)
__device__ __forceinline__ unsigned cvt2bf(float lo, float hi) {
  unsigned r;
  asm("v_cvt_pk_bf16_f32 %0, %1, %2" : "=v"(r) : "v"(lo), "v"(hi));
  return r;
}

// ---------------- kernel 1: B'[m,d] = bf16(u*w3 + w1); c[m] = u . w2 ----------------
__global__ void prep_b_kernel(const float* __restrict__ u, const float* __restrict__ w,
                              short* __restrict__ Bp, float* __restrict__ cvec) {
  int m = blockIdx.x;      // 1024 blocks
  int t = threadIdx.x;     // 256 threads, 4 elems each
  float4 uv = ((const float4*)(u + (size_t)m * Dd))[t];
  float4 w1 = ((const float4*)(w))[t];
  float4 w2 = ((const float4*)(w + Dd))[t];
  float4 w3 = ((const float4*)(w + 2 * Dd))[t];
  float p = uv.x * w2.x + uv.y * w2.y + uv.z * w2.z + uv.w * w2.w;
  short4v o;
  o[0] = f2bf(fmaf(uv.x, w3.x, w1.x));
  o[1] = f2bf(fmaf(uv.y, w3.y, w1.y));
  o[2] = f2bf(fmaf(uv.z, w3.z, w1.z));
  o[3] = f2bf(fmaf(uv.w, w3.w, w1.w));
  *(short4v*)(Bp + (size_t)m * Dd + t * 4) = o;

#pragma unroll
  for (int off = 32; off > 0; off >>= 1) p += __shfl_down(p, off);
  __shared__ float sred[4];
  if ((t & 63) == 0) sred[t >> 6] = p;
  __syncthreads();
  if (t == 0) cvec[m] = sred[0] + sred[1] + sred[2] + sred[3];
}

// ---------------- kernel 2: fused GEMM  S = bf16(h) @ B'^T + c ----------------
// 128x128 tile, BK=64, **512 threads = 8 waves (2Mx4N), wave-tile 64x32**.
// 512 blocks x 8 waves = 4096 waves = 4 waves/SIMD at 2 blocks/CU -- double
// R5's TLP (the binding constraint per R1-R6 post-mortems).
// A: fp32 -> regs (issued BEFORE compute), v_cvt_pk_bf16_f32, 2x ds_write_b128
//    AFTER compute into other buffer (T14). Write-side XOR swizzle on chunk idx.
// B: global_load_lds 16B, pre-swizzled global source (R0-proven), prefetch 1 ahead.
// One s_barrier per K-tile with vmcnt(0)+lgkmcnt(0) (R5-proven acquire/release).
__global__ __launch_bounds__(512, 4) void gemm_fused_kernel(
    const float* __restrict__ h,   // N x D fp32
    const short* __restrict__ B,   // M x D bf16 (B')
    const float* __restrict__ cvec,// M
    float* __restrict__ out)       // N x M fp32
{
  __shared__ __align__(16) short As[2][128 * 64];  // 32 KB
  __shared__ __align__(16) short Bs[2][128 * 64];  // 32 KB

  const int bid = blockIdx.x;
  // bijective XCD swizzle: 512 blocks, 64 per XCD; M-dim fastest within XCD
  const int swz  = (bid & 7) * 64 + (bid >> 3);
  const int brow = swz >> 3;   // 0..63
  const int bcol = swz & 7;    // 0..7

  const int tid  = threadIdx.x;
  const int lane = tid & 63;
  const int wid  = tid >> 6;   // 0..7

  // --- B staging (global_load_lds, pre-swizzled source): wave stages 16 rows ---
  const int l8 = lane >> 3;                 // 0..7
  const int kc = (lane & 7) ^ l8;           // pre-swizzled 16B-chunk index
  const short* Bg = B + (size_t)(bcol * 128 + wid * 16 + l8) * Dd + kc * 8;
  const int BsOff = (wid * 16) * 64;

  // --- A reg-staging: thread t -> row t>>2 (0..127), 16-elem k-group t&3 ---
  const int arow = tid >> 2;
  const int akq  = tid & 3;
  const float* hg = h + (size_t)(brow * 128 + arow) * Dd + akq * 16;
  const int asw  = (arow & 7) << 4;
  const int abyte0 = arow * 128 + ((akq * 32) ^ asw);
  const int abyte1 = arow * 128 + ((akq * 32 + 16) ^ asw);

  // --- fragment reads: 8 waves as 2M x 4N, wave-tile 64x32 ---
  const int wr = wid >> 2;                 // 0..1
  const int wc = wid & 3;                  // 0..3
  const int arow0 = wr * 64 + (lane & 15);
  const int brow0 = wc * 32 + (lane & 15);
  const int kb = (lane >> 4) * 16;
  const int sw = (lane & 7) << 4;

  f32x4 acc[4][2] = {};
  const int NT = Dd / 64;  // 16 K-tiles

#define STAGE_B(buf, kt) do { \
    const short* Bgk_ = Bg + (size_t)(kt) * 64; \
    __builtin_amdgcn_global_load_lds((gas_p)(Bgk_),            (las_p)(&Bs[buf][BsOff]),          16, 0, 0); \
    __builtin_amdgcn_global_load_lds((gas_p)(Bgk_ + 8 * Dd),   (las_p)(&Bs[buf][BsOff + 8 * 64]), 16, 0, 0); \
  } while (0)

#define LOAD_A(kt) do { \
    const float* ab_ = hg + (size_t)(kt) * 64; \
    av0 = *(const float4*)(ab_); \
    av1 = *(const float4*)(ab_ + 4); \
    av2 = *(const float4*)(ab_ + 8); \
    av3 = *(const float4*)(ab_ + 12); \
  } while (0)

#define WRITE_A(buf) do { \
    uint4v q_; \
    q_[0] = cvt2bf(av0.x, av0.y); q_[1] = cvt2bf(av0.z, av0.w); \
    q_[2] = cvt2bf(av1.x, av1.y); q_[3] = cvt2bf(av1.z, av1.w); \
    *(uint4v*)((char*)&As[buf][0] + abyte0) = q_; \
    q_[0] = cvt2bf(av2.x, av2.y); q_[1] = cvt2bf(av2.z, av2.w); \
    q_[2] = cvt2bf(av3.x, av3.y); q_[3] = cvt2bf(av3.z, av3.w); \
    *(uint4v*)((char*)&As[buf][0] + abyte1) = q_; \
  } while (0)

  // ---- prologue: stage tile 0 into buffer 0 ----
  {
    float4 av0, av1, av2, av3;
    STAGE_B(0, 0);
    LOAD_A(0);
    WRITE_A(0);
    asm volatile("s_waitcnt vmcnt(0)" ::: "memory");
    asm volatile("s_waitcnt lgkmcnt(0)" ::: "memory");
    __builtin_amdgcn_s_barrier();
  }

  int cur = 0;
#pragma unroll 1
  for (int kt = 0; kt < NT; ++kt) {
    float4 av0, av1, av2, av3;
    const bool pf = (kt + 1 < NT);
    if (pf) {
      STAGE_B(cur ^ 1, kt + 1);   // issue next-tile B staging
      LOAD_A(kt + 1);             // issue next-tile A loads (latency hides under compute)
    }
    // ---- compute current buffer ----
#pragma unroll
    for (int kk = 0; kk < 2; ++kk) {
      short8 af[4], bfr[2];
      const int koff = kk * 64 + kb;
#pragma unroll
      for (int i = 0; i < 4; ++i)
        af[i]  = *(const short8*)((const char*)&As[cur][0] + ((arow0 + i * 16) * 128 + (koff ^ sw)));
#pragma unroll
      for (int j = 0; j < 2; ++j)
        bfr[j] = *(const short8*)((const char*)&Bs[cur][0] + ((brow0 + j * 16) * 128 + (koff ^ sw)));
#pragma unroll
      for (int i = 0; i < 4; ++i)
#pragma unroll
        for (int j = 0; j < 2; ++j)
          acc[i][j] = __builtin_amdgcn_mfma_f32_16x16x32_bf16(af[i], bfr[j], acc[i][j], 0, 0, 0);
    }
    if (pf) WRITE_A(cur ^ 1);     // convert + ds_write A(kt+1) after compute
    asm volatile("s_waitcnt vmcnt(0)" ::: "memory");   // B(kt+1) staged; A regs landed
    asm volatile("s_waitcnt lgkmcnt(0)" ::: "memory"); // my ds_writes/reads retired
    __builtin_amdgcn_s_barrier();
    cur ^= 1;
  }
#undef STAGE_B
#undef LOAD_A
#undef WRITE_A

  // --- epilogue: S[n,m] = acc + c[m] (proven C/D mapping) ---
  const int n0 = brow * 128 + wr * 64 + (lane >> 4) * 4;
  const int m0 = bcol * 128 + wc * 32 + (lane & 15);
#pragma unroll
  for (int j = 0; j < 2; ++j) {
    const float cm = cvec[m0 + j * 16];
#pragma unroll
    for (int i = 0; i < 4; ++i) {
      float* op = out + (size_t)(n0 + i * 16) * Mm + m0 + j * 16;
#pragma unroll
      for (int r = 0; r < 4; ++r)
        op[(size_t)r * Mm] = acc[i][j][r] + cm;
    }
  }
}

extern "C" void kernel_launch(void* const* d_in, const int* in_sizes, int n_in,
                              void* d_out, int out_size, void* d_ws, size_t ws_size,
                              hipStream_t stream) {
  const float* h = (const float*)d_in[0];
  const float* u = (const float*)d_in[1];
  const float* w = (const float*)d_in[2];
  float* out = (float*)d_out;

  // workspace layout: B' bf16 (2MB) | c fp32 (4KB)
  short* Bp  = (short*)d_ws;
  float* cvec = (float*)(Bp + (size_t)Mm * Dd);

  prep_b_kernel<<<Mm, 256, 0, stream>>>(u, w, Bp, cvec);
  gemm_fused_kernel<<<(Nn / 128) * (Mm / 128), 512, 0, stream>>>(h, Bp, cvec, out);
}